// Round 4
// baseline (1346.379 us; speedup 1.0000x reference)
//
#include <hip/hip_runtime.h>

// out = input; out[index[i,j], j] += src[i,j]
// input: [65536,64] f32 ; index: [1e6,64] i32 ; src: [1e6,64] f32
// R4: no hist/scan kernels. Scatter bins into fixed per-bucket regions
// (atomic batch reservation), direct global pair writes (L2-coalesced).
// Reduce: per-bucket LDS tile accumulate fused with out += tile.

typedef unsigned int u32;
typedef unsigned short u16;

#define NBKT 256        // buckets (row >> 8)
#define CAPB 262144     // pairs per bucket region (2^18; mean 250K + 24 sigma)
#define BLK 512         // scatter block threads
#define EPB 16384       // elements per scatter block
#define GROUPS 8        // EPB / (BLK*4)
#define TILE 16384      // floats per bucket tile (256 rows * 64 cols)

// ---------------- out = input (+ zero gcnt) ----------------
__global__ void InitOut_kernel(const float4* __restrict__ in, float4* __restrict__ out,
                               int n4, u32* gcnt) {
    int i = blockIdx.x * blockDim.x + threadIdx.x;
    if (i < n4) out[i] = in[i];
    if (gcnt && blockIdx.x == 0 && threadIdx.x < NBKT) gcnt[threadIdx.x] = 0;
}

// ---------------- fallback: direct atomics ----------------
__global__ void FallbackAdd_kernel(const int4* __restrict__ index4,
                                   const float4* __restrict__ src4,
                                   float* __restrict__ out, int n4) {
    const int stride = gridDim.x * blockDim.x;
    for (int i = blockIdx.x * blockDim.x + threadIdx.x; i < n4; i += stride) {
        int4 idx = index4[i];
        float4 v = src4[i];
        int jbase = (i & 15) << 2;
        atomicAdd(&out[(idx.x << 6) + jbase + 0], v.x);
        atomicAdd(&out[(idx.y << 6) + jbase + 1], v.y);
        atomicAdd(&out[(idx.z << 6) + jbase + 2], v.z);
        atomicAdd(&out[(idx.w << 6) + jbase + 3], v.w);
    }
}

// ---------------- scatter: hist -> reserve -> direct pair write ----------------
__global__ __launch_bounds__(BLK) void Scatter_kernel(const int* __restrict__ index,
        const float* __restrict__ src,
        u32* __restrict__ gcnt,
        float* __restrict__ val, u16* __restrict__ dst,
        float* __restrict__ out,
        long long E) {
    __shared__ u32 h[NBKT];
    __shared__ u32 base[NBKT];
    __shared__ u32 cnt2[NBKT];
    int t = threadIdx.x;
    long long b0 = (long long)blockIdx.x * EPB;
    if (t < NBKT) h[t] = 0;
    __syncthreads();

    int4 rg[GROUPS];
    #pragma unroll
    for (int g = 0; g < GROUPS; ++g) {
        long long e = b0 + (long long)g * (BLK * 4) + t * 4;
        if (e < E) {
            rg[g] = *(const int4*)(index + e);
            atomicAdd(&h[rg[g].x >> 8], 1u);
            atomicAdd(&h[rg[g].y >> 8], 1u);
            atomicAdd(&h[rg[g].z >> 8], 1u);
            atomicAdd(&h[rg[g].w >> 8], 1u);
        }
    }
    __syncthreads();
    if (t < NBKT) {
        base[t] = atomicAdd(&gcnt[t], h[t]);   // coalesced 256-wide reservation
        cnt2[t] = 0;
    }
    __syncthreads();

    int col0 = (t << 2) & 63;   // group stride (BLK*4=2048) is a multiple of 64
    #pragma unroll
    for (int g = 0; g < GROUPS; ++g) {
        long long e = b0 + (long long)g * (BLK * 4) + t * 4;
        if (e < E) {
            float4 v = *(const float4*)(src + e);
#define PROC(rr, vv, cc) { \
            int bb = (rr) >> 8; \
            u32 p = atomicAdd(&cnt2[bb], 1u); \
            u32 o = base[bb] + p; \
            if (o < CAPB) { \
                size_t pos = ((size_t)bb << 18) + o; \
                val[pos] = (vv); \
                dst[pos] = (u16)((((rr) & 255) << 6) | (cc)); \
            } else { \
                atomicAdd(&out[((size_t)(rr) << 6) + (cc)], (vv)); \
            } }
            PROC(rg[g].x, v.x, col0 + 0);
            PROC(rg[g].y, v.y, col0 + 1);
            PROC(rg[g].z, v.z, col0 + 2);
            PROC(rg[g].w, v.w, col0 + 3);
#undef PROC
        }
    }
}

// ---------------- reduce: LDS tile accumulate + out += tile ----------------
__global__ __launch_bounds__(1024) void Reduce_kernel(const float* __restrict__ val,
                                                      const u16* __restrict__ dst,
                                                      const u32* __restrict__ gcnt,
                                                      float* __restrict__ out) {
    __shared__ float tile[TILE];            // 64 KB
    int b = blockIdx.x, t = threadIdx.x;
    float4* t4 = (float4*)tile;
    for (int i = t; i < TILE / 4; i += 1024) t4[i] = make_float4(0.f, 0.f, 0.f, 0.f);
    __syncthreads();
    u32 n = gcnt[b]; if (n > CAPB) n = CAPB;
    const float4* v4 = (const float4*)(val + ((size_t)b << 18));
    const ushort4* d4 = (const ushort4*)(dst + ((size_t)b << 18));
    u32 n4 = n >> 2;
    for (u32 i = t; i < n4; i += 1024) {
        float4 v = v4[i]; ushort4 d = d4[i];
        atomicAdd(&tile[d.x], v.x);
        atomicAdd(&tile[d.y], v.y);
        atomicAdd(&tile[d.z], v.z);
        atomicAdd(&tile[d.w], v.w);
    }
    for (u32 i = (n4 << 2) + t; i < n; i += 1024) {
        atomicAdd(&tile[dst[((size_t)b << 18) + i]], val[((size_t)b << 18) + i]);
    }
    __syncthreads();
    float4* o4 = (float4*)(out + (size_t)b * TILE);
    for (int i = t; i < TILE / 4; i += 1024) {
        float4 a = o4[i], s = t4[i];
        a.x += s.x; a.y += s.y; a.z += s.z; a.w += s.w;
        o4[i] = a;
    }
}

extern "C" void kernel_launch(void* const* d_in, const int* in_sizes, int n_in,
                              void* d_out, int out_size, void* d_ws, size_t ws_size,
                              hipStream_t stream) {
    const float* input = (const float*)d_in[0];
    const int*   index = (const int*)d_in[1];
    const float* src   = (const float*)d_in[2];
    float* out = (float*)d_out;
    long long E = (long long)in_sizes[2];          // 64,000,000

    // ws layout: gcnt u32[256] @0 | val f32[NBKT*CAPB] @4K | dst u16[NBKT*CAPB]
    char* ws = (char*)d_ws;
    size_t offV = 4096;
    size_t offD = offV + (size_t)NBKT * CAPB * 4;  // 256 MB
    size_t need = offD + (size_t)NBKT * CAPB * 2;  // +128 MB

    int n4o = out_size / 4;

    if (ws_size < need || (E & 4095) || out_size != NBKT * TILE) {
        InitOut_kernel<<<(n4o + 255) / 256, 256, 0, stream>>>(
            (const float4*)input, (float4*)out, n4o, nullptr);
        FallbackAdd_kernel<<<2048, 256, 0, stream>>>(
            (const int4*)index, (const float4*)src, out, (int)(E / 4));
        return;
    }

    u32*  gcnt = (u32*)ws;
    float* val = (float*)(ws + offV);
    u16*  dst  = (u16*)(ws + offD);

    InitOut_kernel<<<(n4o + 255) / 256, 256, 0, stream>>>(
        (const float4*)input, (float4*)out, n4o, gcnt);

    int nblk = (int)((E + EPB - 1) / EPB);         // 3907
    Scatter_kernel<<<nblk, BLK, 0, stream>>>(index, src, gcnt, val, dst, out, E);

    Reduce_kernel<<<NBKT, 1024, 0, stream>>>(val, dst, gcnt, out);
}

// Round 6
// 698.063 us; speedup vs baseline: 1.9287x; 1.9287x over previous
//
#include <hip/hip_runtime.h>

// out = input; out[index[i,j], j] += src[i,j]
// input: [65536,64] f32 ; index: [1e6,64] i32 ; src: [1e6,64] f32
// R6 = R5 with the column-offset bug fixed (epb must be a multiple of 64
// because col0 = (t*4)&63 assumes c0 % 64 == 0), memset -> zero kernel.
// Structure: 1024 persistent scatter blocks, fixed per-(bucket,block) runs,
// LDS-staged sector-aligned flushes (multiples of 8 pairs), index read once.
// Reduce: per-bucket 64KB LDS tile accumulate fused with out = input + tile.

typedef unsigned int u32;
typedef unsigned short u16;
typedef unsigned long long u64;

#define NBKT 256        // buckets (row >> 8)
#define NBLK 1024       // scatter blocks (persistent, 4/CU)
#define BLK  512        // scatter block threads
#define BATCH 2048      // elements per batch (BLK*4)
#define CAPR 320        // run slots per (bucket,block): mean ~244 + ~4.9 sigma
#define CAPS 24         // staged slots per bucket (LDS)
#define TILE 16384      // floats per bucket tile (256 rows * 64 cols)
#define OMAX 130048     // overflow list capacity

__global__ void Zero_kernel(u32* p, int n) {
    int i = threadIdx.x;
    if (i < n) p[i] = 0;
}

// ---------------- fallback path ----------------
__global__ void InitOut_kernel(const float4* __restrict__ in, float4* __restrict__ out, int n4) {
    int i = blockIdx.x * blockDim.x + threadIdx.x;
    if (i < n4) out[i] = in[i];
}

__global__ void FallbackAdd_kernel(const int4* __restrict__ index4,
                                   const float4* __restrict__ src4,
                                   float* __restrict__ out, int n4) {
    const int stride = gridDim.x * blockDim.x;
    for (int i = blockIdx.x * blockDim.x + threadIdx.x; i < n4; i += stride) {
        int4 idx = index4[i];
        float4 v = src4[i];
        int jbase = (i & 15) << 2;
        atomicAdd(&out[(idx.x << 6) + jbase + 0], v.x);
        atomicAdd(&out[(idx.y << 6) + jbase + 1], v.y);
        atomicAdd(&out[(idx.z << 6) + jbase + 2], v.z);
        atomicAdd(&out[(idx.w << 6) + jbase + 3], v.w);
    }
}

// ---------------- scatter: persistent blocks, staged aligned flush ----------------
__global__ __launch_bounds__(BLK) void Scatter_kernel(
        const int* __restrict__ index, const float* __restrict__ src,
        float* __restrict__ val, u16* __restrict__ dst, u16* __restrict__ cntg,
        u32* __restrict__ ocnt, u64* __restrict__ olist,
        int epb, long long E)
{
    __shared__ float sv[NBKT][CAPS];    // 24 KB
    __shared__ u16  sd[NBKT][CAPS];     // 12 KB
    __shared__ u32  cnt[NBKT];          // absolute rank per bucket
    __shared__ u32  flushed[NBKT];      // pairs already in global (per bucket)
    const int t = threadIdx.x;
    const int k = blockIdx.x;
    long long c0 = (long long)k * epb;  // epb % 64 == 0 -> c0 % 64 == 0
    long long c1 = c0 + epb; if (c1 > E) c1 = E;
    if (c0 >= c1) {                     // empty chunk: publish zero counts
        if (t < NBKT) cntg[(size_t)k * NBKT + t] = 0;
        return;
    }
    if (t < NBKT) { cnt[t] = 0; flushed[t] = 0; }
    __syncthreads();

    const int col0 = (t << 2) & 63;         // valid: c0 and BATCH are multiples of 64
    const size_t rbase = (size_t)k * CAPR;  // + b*(NBLK*CAPR) gives run start

#define PROC(rr, vv, cc) { \
    int bb = (rr) >> 8; \
    u32 p = atomicAdd(&cnt[bb], 1u); \
    if (p < CAPR) { \
        u32 fl = flushed[bb]; \
        u32 slot = p - fl; \
        u16 dd = (u16)((((rr) & 255) << 6) | (cc)); \
        if (slot < CAPS) { sv[bb][slot] = (vv); sd[bb][slot] = dd; } \
        else { size_t pos = (size_t)bb * (NBLK * CAPR) + rbase + p; \
               val[pos] = (vv); dst[pos] = dd; } \
    } else { \
        u32 oi = atomicAdd(ocnt, 1u); \
        if (oi < OMAX) \
            olist[oi] = ((u64)__float_as_uint(vv) << 32) | (u32)(((rr) << 6) + (cc)); \
    } }

    long long e = c0 + t * 4;
    int4 r; float4 v;
    bool have = e < c1;                    // chunk length is a multiple of 4
    if (have) { r = *(const int4*)(index + e); v = *(const float4*)(src + e); }

    const int g = t >> 3, lr = t & 7;

    for (long long eb = c0; eb < c1; eb += BATCH) {
        if (have) {
            PROC(r.x, v.x, col0 + 0);
            PROC(r.y, v.y, col0 + 1);
            PROC(r.z, v.z, col0 + 2);
            PROC(r.w, v.w, col0 + 3);
        }
        // prefetch next batch (independent of LDS; overlaps the flush)
        long long en = e + BATCH;
        bool haveN = en < c1;
        int4 rn; float4 vn;
        if (haveN) { rn = *(const int4*)(index + en); vn = *(const float4*)(src + en); }
        __syncthreads();
        // flush: 8 lanes per bucket, 64 buckets per pass, multiples of 8 pairs
        #pragma unroll
        for (int pass = 0; pass < 4; ++pass) {
            int b = (pass << 6) + g;
            u32 c = cnt[b]; if (c > CAPR) c = CAPR;
            u32 fl = flushed[b];
            u32 staged = c - fl;
            u32 fcopy, rem, newfl;
            if (staged > CAPS) { fcopy = CAPS; rem = 0; newfl = c; }   // rest went direct
            else { fcopy = staged & ~7u; rem = staged - fcopy; newfl = fl + fcopy; }
            size_t rb = (size_t)b * (NBLK * CAPR) + rbase + fl;
            for (u32 i = lr; i < fcopy; i += 8) {
                val[rb + i] = sv[b][i];
                dst[rb + i] = sd[b][i];
            }
            if (lr < rem) {               // carry remainder down (fcopy is 0 or >=8: safe)
                sv[b][lr] = sv[b][fcopy + lr];
                sd[b][lr] = sd[b][fcopy + lr];
            }
            if (lr == 0) flushed[b] = newfl;
        }
        __syncthreads();
        r = rn; v = vn; have = haveN; e = en;
    }

    // final flush of remainders (<8 per bucket, unaligned tail ok)
    #pragma unroll
    for (int pass = 0; pass < 4; ++pass) {
        int b = (pass << 6) + g;
        u32 c = cnt[b]; if (c > CAPR) c = CAPR;
        u32 fl = flushed[b];
        u32 staged = c - fl;
        u32 fcopy = staged > CAPS ? CAPS : staged;
        size_t rb = (size_t)b * (NBLK * CAPR) + rbase + fl;
        for (u32 i = lr; i < fcopy; i += 8) {
            val[rb + i] = sv[b][i];
            dst[rb + i] = sd[b][i];
        }
    }
    __syncthreads();
    if (t < NBKT) {
        u32 c = cnt[t]; if (c > CAPR) c = CAPR;
        cntg[(size_t)k * NBKT + t] = (u16)c;
    }
#undef PROC
}

// ---------------- reduce: LDS tile accumulate + out = input + tile ----------------
__global__ __launch_bounds__(1024) void Reduce_kernel(
        const float* __restrict__ val, const u16* __restrict__ dst,
        const u16* __restrict__ cntg, const u32* __restrict__ ocnt,
        const u64* __restrict__ olist,
        const float* __restrict__ input, float* __restrict__ out)
{
    __shared__ float tile[TILE];            // 64 KB
    const int b = blockIdx.x, t = threadIdx.x;
    float4* t4 = (float4*)tile;
    for (int i = t; i < TILE / 4; i += 1024) t4[i] = make_float4(0.f, 0.f, 0.f, 0.f);
    __syncthreads();
    const int g = t >> 3, lr = t & 7;       // 128 groups of 8 lanes
    const size_t bb = (size_t)b * (NBLK * CAPR);
    for (int k = g; k < NBLK; k += 128) {
        u32 n = cntg[(size_t)k * NBKT + b]; if (n > CAPR) n = CAPR;
        const float* vp = val + bb + (size_t)k * CAPR;
        const u16*  dp = dst + bb + (size_t)k * CAPR;
        for (u32 i = lr; i < n; i += 8)
            atomicAdd(&tile[dp[i]], vp[i]);
    }
    __syncthreads();
    u32 on = *ocnt; if (on > OMAX) on = OMAX;
    for (u32 i = t; i < on; i += 1024) {
        u64 pr = olist[i];
        u32 d = (u32)pr;
        if ((d >> 14) == (u32)b)
            atomicAdd(&tile[d & (TILE - 1)], __uint_as_float((u32)(pr >> 32)));
    }
    __syncthreads();
    const float4* in4 = (const float4*)(input + (size_t)b * TILE);
    float4* o4 = (float4*)(out + (size_t)b * TILE);
    for (int i = t; i < TILE / 4; i += 1024) {
        float4 a = in4[i], s = t4[i];
        a.x += s.x; a.y += s.y; a.z += s.z; a.w += s.w;
        o4[i] = a;
    }
}

extern "C" void kernel_launch(void* const* d_in, const int* in_sizes, int n_in,
                              void* d_out, int out_size, void* d_ws, size_t ws_size,
                              hipStream_t stream) {
    const float* input = (const float*)d_in[0];
    const int*   index = (const int*)d_in[1];
    const float* src   = (const float*)d_in[2];
    float* out = (float*)d_out;
    long long E = (long long)in_sizes[2];          // 64,000,000

    // ws layout
    const size_t off_olist = 64;
    const size_t off_cnt   = off_olist + (size_t)OMAX * 8;               // ~1.04 MB
    const size_t off_val   = (size_t)2u << 20;                           // 2 MB
    const size_t off_dst   = off_val + (size_t)NBKT * NBLK * CAPR * 4;   // +335.5 MB
    const size_t need      = off_dst + (size_t)NBKT * NBLK * CAPR * 2;   // 505.4 MB

    // epb MUST be a multiple of 64 so every chunk starts at column 0
    int epb = (int)(((E + NBLK - 1) / NBLK + 63) & ~63LL);   // 62528 for E=64M

    int n4o = out_size / 4;
    if (ws_size < need || (E & 3) || out_size != NBKT * TILE || epb > 65536) {
        InitOut_kernel<<<(n4o + 255) / 256, 256, 0, stream>>>(
            (const float4*)input, (float4*)out, n4o);
        FallbackAdd_kernel<<<2048, 256, 0, stream>>>(
            (const int4*)index, (const float4*)src, out, (int)(E / 4));
        return;
    }

    char* ws = (char*)d_ws;
    u32*  ocnt  = (u32*)ws;
    u64*  olist = (u64*)(ws + off_olist);
    u16*  cntg  = (u16*)(ws + off_cnt);
    float* val  = (float*)(ws + off_val);
    u16*  dst   = (u16*)(ws + off_dst);

    Zero_kernel<<<1, 64, 0, stream>>>(ocnt, 16);

    Scatter_kernel<<<NBLK, BLK, 0, stream>>>(index, src, val, dst, cntg,
                                             ocnt, olist, epb, E);
    Reduce_kernel<<<NBKT, 1024, 0, stream>>>(val, dst, cntg, ocnt, olist, input, out);
}

// Round 7
// 622.585 us; speedup vs baseline: 2.1626x; 1.1212x over previous
//
#include <hip/hip_runtime.h>

// out = input; out[index[i,j], j] += src[i,j]
// input: [65536,64] f32 ; index: [1e6,64] i32 ; src: [1e6,64] f32
// R7: scatter flush unit = 16 pairs (val 64B / dst 32B granule-aligned pieces),
// stage stride 31 (odd -> full LDS bank spread), reduce split 2 blocks/bucket
// with float4 pair loads and out pre-initialized from input.

typedef unsigned int u32;
typedef unsigned short u16;
typedef unsigned long long u64;

#define NBKT 256        // buckets (row >> 8)
#define NBLK 1024       // scatter blocks
#define BLK  512        // scatter block threads
#define BATCH 2048      // elements per batch (BLK*4)
#define CAPR 320        // run slots per (bucket,block): mean ~244 + ~4.9 sigma
#define CAPS 30         // staged slots per bucket (LDS)
#define CPAD 31         // padded stride (odd -> bank = (31*b+slot)%32 uniform)
#define FU   16         // flush unit (pairs): val 64B, dst 32B pieces
#define TILE 16384      // floats per bucket tile (256 rows * 64 cols)
#define OMAX 130048     // overflow list capacity

__global__ void Zero_kernel(u32* p, int n) {
    int i = threadIdx.x;
    if (i < n) p[i] = 0;
}

__global__ void InitOut_kernel(const float4* __restrict__ in, float4* __restrict__ out, int n4) {
    int i = blockIdx.x * blockDim.x + threadIdx.x;
    if (i < n4) out[i] = in[i];
}

__global__ void FallbackAdd_kernel(const int4* __restrict__ index4,
                                   const float4* __restrict__ src4,
                                   float* __restrict__ out, int n4) {
    const int stride = gridDim.x * blockDim.x;
    for (int i = blockIdx.x * blockDim.x + threadIdx.x; i < n4; i += stride) {
        int4 idx = index4[i];
        float4 v = src4[i];
        int jbase = (i & 15) << 2;
        atomicAdd(&out[(idx.x << 6) + jbase + 0], v.x);
        atomicAdd(&out[(idx.y << 6) + jbase + 1], v.y);
        atomicAdd(&out[(idx.z << 6) + jbase + 2], v.z);
        atomicAdd(&out[(idx.w << 6) + jbase + 3], v.w);
    }
}

// ---------------- scatter: persistent blocks, 16-pair aligned flush ----------------
__global__ __launch_bounds__(BLK) void Scatter_kernel(
        const int* __restrict__ index, const float* __restrict__ src,
        float* __restrict__ val, u16* __restrict__ dst, u16* __restrict__ cntg,
        u32* __restrict__ ocnt, u64* __restrict__ olist,
        int epb, long long E)
{
    __shared__ float sv[NBKT][CPAD];    // 31 KB
    __shared__ u16  sd[NBKT][CPAD];     // 15.5 KB
    __shared__ u32  cnt[NBKT];          // absolute rank per bucket
    __shared__ u32  flushed[NBKT];      // pairs already in global (per bucket)
    const int t = threadIdx.x;
    const int k = blockIdx.x;
    long long c0 = (long long)k * epb;  // epb % 64 == 0 -> c0 % 64 == 0
    long long c1 = c0 + epb; if (c1 > E) c1 = E;
    if (c0 >= c1) {
        if (t < NBKT) cntg[(size_t)k * NBKT + t] = 0;
        return;
    }
    if (t < NBKT) { cnt[t] = 0; flushed[t] = 0; }
    __syncthreads();

    const int col0 = (t << 2) & 63;         // valid: c0 and BATCH are multiples of 64
    const size_t rbase = (size_t)k * CAPR;

#define PROC(rr, vv, cc) { \
    int bb = (rr) >> 8; \
    u32 p = atomicAdd(&cnt[bb], 1u); \
    if (p < CAPR) { \
        u32 fl = flushed[bb]; \
        u32 slot = p - fl; \
        u16 dd = (u16)((((rr) & 255) << 6) | (cc)); \
        if (slot < CAPS) { sv[bb][slot] = (vv); sd[bb][slot] = dd; } \
        else { size_t pos = (size_t)bb * (NBLK * CAPR) + rbase + p; \
               val[pos] = (vv); dst[pos] = dd; } \
    } else { \
        u32 oi = atomicAdd(ocnt, 1u); \
        if (oi < OMAX) \
            olist[oi] = ((u64)__float_as_uint(vv) << 32) | (u32)(((rr) << 6) + (cc)); \
    } }

    long long e = c0 + t * 4;
    int4 r; float4 v;
    bool have = e < c1;
    if (have) { r = *(const int4*)(index + e); v = *(const float4*)(src + e); }

    const int g = t >> 3, lr = t & 7;

    for (long long eb = c0; eb < c1; eb += BATCH) {
        if (have) {
            PROC(r.x, v.x, col0 + 0);
            PROC(r.y, v.y, col0 + 1);
            PROC(r.z, v.z, col0 + 2);
            PROC(r.w, v.w, col0 + 3);
        }
        long long en = e + BATCH;
        bool haveN = en < c1;
        int4 rn; float4 vn;
        if (haveN) { rn = *(const int4*)(index + en); vn = *(const float4*)(src + en); }
        __syncthreads();
        // flush multiples of FU=16 pairs; 8 lanes per bucket, 64 buckets/pass
        #pragma unroll
        for (int pass = 0; pass < 4; ++pass) {
            int b = (pass << 6) + g;
            u32 c = cnt[b]; if (c > CAPR) c = CAPR;
            u32 fl = flushed[b];
            u32 staged = c - fl;
            u32 fcopy, rem, newfl;
            if (staged > CAPS) { fcopy = CAPS; rem = 0; newfl = c; }   // rest went direct
            else { fcopy = staged & ~(FU - 1u); rem = staged - fcopy; newfl = fl + fcopy; }
            size_t rb = (size_t)b * (NBLK * CAPR) + rbase + fl;
            for (u32 i = lr; i < fcopy; i += 8) {
                val[rb + i] = sv[b][i];
                dst[rb + i] = sd[b][i];
            }
            for (u32 i = lr; i < rem; i += 8) {    // carry (<=15) down; fcopy 0 or >=16: no overlap
                sv[b][i] = sv[b][fcopy + i];
                sd[b][i] = sd[b][fcopy + i];
            }
            if (lr == 0) flushed[b] = newfl;
        }
        __syncthreads();
        r = rn; v = vn; have = haveN; e = en;
    }

    // final flush of remainders (<FU per bucket, unaligned tail ok)
    #pragma unroll
    for (int pass = 0; pass < 4; ++pass) {
        int b = (pass << 6) + g;
        u32 c = cnt[b]; if (c > CAPR) c = CAPR;
        u32 fl = flushed[b];
        u32 staged = c - fl;
        u32 fcopy = staged > CAPS ? CAPS : staged;
        size_t rb = (size_t)b * (NBLK * CAPR) + rbase + fl;
        for (u32 i = lr; i < fcopy; i += 8) {
            val[rb + i] = sv[b][i];
            dst[rb + i] = sd[b][i];
        }
    }
    __syncthreads();
    if (t < NBKT) {
        u32 c = cnt[t]; if (c > CAPR) c = CAPR;
        cntg[(size_t)k * NBKT + t] = (u16)c;
    }
#undef PROC
}

// ---------------- reduce: 2 blocks/bucket, float4 pair loads, tile -> atomic out ----------------
__global__ __launch_bounds__(512) void Reduce_kernel(
        const float* __restrict__ val, const u16* __restrict__ dst,
        const u16* __restrict__ cntg, const u32* __restrict__ ocnt,
        const u64* __restrict__ olist, float* __restrict__ out)
{
    __shared__ float tile[TILE];            // 64 KB -> 2 blocks/CU
    const int b = blockIdx.x >> 1;
    const int p = blockIdx.x & 1;
    const int t = threadIdx.x;
    float4* t4 = (float4*)tile;
    for (int i = t; i < TILE / 4; i += 512) t4[i] = make_float4(0.f, 0.f, 0.f, 0.f);
    __syncthreads();
    const int g = t >> 3, lr = t & 7;       // 64 groups of 8 lanes
    const size_t bb = (size_t)b * ((size_t)NBLK * CAPR);
    for (int k = p * (NBLK / 2) + g; k < (p + 1) * (NBLK / 2); k += 64) {
        u32 n = cntg[(size_t)k * NBKT + b]; if (n > CAPR) n = CAPR;
        const float* vp = val + bb + (size_t)k * CAPR;
        const u16*  dp = dst + bb + (size_t)k * CAPR;
        u32 n4 = n & ~3u;
        for (u32 i = lr * 4; i + 4 <= n4 + 4 && i < n4; i += 32) {
            float4 v = *(const float4*)(vp + i);
            ushort4 d = *(const ushort4*)(dp + i);
            atomicAdd(&tile[d.x], v.x);
            atomicAdd(&tile[d.y], v.y);
            atomicAdd(&tile[d.z], v.z);
            atomicAdd(&tile[d.w], v.w);
        }
        u32 rem = n - n4;
        if ((u32)lr < rem)
            atomicAdd(&tile[dp[n4 + lr]], vp[n4 + lr]);
    }
    if (p == 0) {
        u32 on = *ocnt; if (on > OMAX) on = OMAX;
        for (u32 i = t; i < on; i += 512) {
            u64 pr = olist[i];
            u32 d = (u32)pr;
            if ((d >> 14) == (u32)b)
                atomicAdd(&tile[d & (TILE - 1)], __uint_as_float((u32)(pr >> 32)));
        }
    }
    __syncthreads();
    float* ob = out + (size_t)b * TILE;
    for (int i = t; i < TILE; i += 512)
        atomicAdd(&ob[i], tile[i]);         // coalesced; out pre-initialized with input
}

extern "C" void kernel_launch(void* const* d_in, const int* in_sizes, int n_in,
                              void* d_out, int out_size, void* d_ws, size_t ws_size,
                              hipStream_t stream) {
    const float* input = (const float*)d_in[0];
    const int*   index = (const int*)d_in[1];
    const float* src   = (const float*)d_in[2];
    float* out = (float*)d_out;
    long long E = (long long)in_sizes[2];          // 64,000,000

    const size_t off_olist = 64;
    const size_t off_cnt   = off_olist + (size_t)OMAX * 8;               // ~1.04 MB
    const size_t off_val   = (size_t)2u << 20;                           // 2 MB
    const size_t off_dst   = off_val + (size_t)NBKT * NBLK * CAPR * 4;   // +335.5 MB
    const size_t need      = off_dst + (size_t)NBKT * NBLK * CAPR * 2;   // 505.4 MB

    // epb MUST be a multiple of 64 so every chunk starts at column 0
    int epb = (int)(((E + NBLK - 1) / NBLK + 63) & ~63LL);   // 62528 for E=64M

    int n4o = out_size / 4;
    if (ws_size < need || (E & 3) || out_size != NBKT * TILE || epb > 65536) {
        InitOut_kernel<<<(n4o + 255) / 256, 256, 0, stream>>>(
            (const float4*)input, (float4*)out, n4o);
        FallbackAdd_kernel<<<2048, 256, 0, stream>>>(
            (const int4*)index, (const float4*)src, out, (int)(E / 4));
        return;
    }

    char* ws = (char*)d_ws;
    u32*  ocnt  = (u32*)ws;
    u64*  olist = (u64*)(ws + off_olist);
    u16*  cntg  = (u16*)(ws + off_cnt);
    float* val  = (float*)(ws + off_val);
    u16*  dst   = (u16*)(ws + off_dst);

    Zero_kernel<<<1, 64, 0, stream>>>(ocnt, 16);
    InitOut_kernel<<<(n4o + 255) / 256, 256, 0, stream>>>(
        (const float4*)input, (float4*)out, n4o);

    Scatter_kernel<<<NBLK, BLK, 0, stream>>>(index, src, val, dst, cntg,
                                             ocnt, olist, epb, E);
    Reduce_kernel<<<NBKT * 2, 512, 0, stream>>>(val, dst, cntg, ocnt, olist, out);
}